// Round 15
// baseline (1017.215 us; speedup 1.0000x reference)
//
#include <hip/hip_runtime.h>
#include <math.h>

#define NN 10000
#define EE 160000
#define EP 170000          // EE + NN self loops
#define NFEAT 256
#define NHID 128
#define NH 4
#define HF 512             // NH * NHID
#define NCLASS 40
#define FCOLS 1088         // 512 xh + 512 res + 8 attn + 56 pad
#define NB 512             // persistent grid: 2 blocks/CU, co-residency guaranteed

typedef __attribute__((ext_vector_type(8))) short bf8;     // 8 bf16 (4 VGPR) MFMA frag
typedef __attribute__((ext_vector_type(8))) unsigned short u16x8;
typedef __attribute__((ext_vector_type(4))) float f4;

__device__ __forceinline__ float leaky02(float x) { return x >= 0.0f ? x : 0.2f * x; }

__device__ __forceinline__ unsigned short f2bf(float f) {   // RNE
    unsigned u = __builtin_bit_cast(unsigned, f);
    unsigned r = (u + 0x7FFF + ((u >> 16) & 1)) >> 16;
    return (unsigned short)r;
}
__device__ __forceinline__ float bf2f(unsigned short h) {
    return __builtin_bit_cast(float, (unsigned)h << 16);
}

// Bank-swizzled element position within a row of length K (baked into GLOBAL layout
// of MFMA operands so global->LDS staging is a LINEAR copy for global_load_lds).
__device__ __forceinline__ int swz(int row, int c) {
    return ((((c >> 3) ^ (row & 7)) << 3) | (c & 7));
}

// 16B global -> LDS direct DMA
__device__ __forceinline__ void gl_lds16(const unsigned short* g, unsigned short* l)
{
    __builtin_amdgcn_global_load_lds(
        (const __attribute__((address_space(1))) unsigned int*)g,
        (__attribute__((address_space(3))) unsigned int*)l, 16, 0, 0);
}

// Device-scope grid barrier (monotonic counter; NOT hipLaunchCooperativeKernel —
// that API fails on this harness, R11). Release fence flushes writer-XCD L2;
// agent-scope acquire load invalidates reader caches (cross-XCD coherence).
__device__ __forceinline__ void grid_sync(int* bar, int target)
{
    __syncthreads();
    if (threadIdx.x == 0) {
        __threadfence();
        __hip_atomic_fetch_add(bar, 1, __ATOMIC_RELEASE, __HIP_MEMORY_SCOPE_AGENT);
        while (__hip_atomic_load(bar, __ATOMIC_ACQUIRE, __HIP_MEMORY_SCOPE_AGENT) < target)
            __builtin_amdgcn_s_sleep(8);
        __threadfence();
    }
    __syncthreads();
}

#define C_X   2560000
#define C_EW  (C_X + 32768)
#define C_FW  (C_EW + 131072)      // gat_w + res_w -> fw rows 0..1023
#define C_DW  (C_FW + 5120)        // dec_w [40,128]
#define CVT_B  1333                // ceil((C_DW/8)/256)
#define ATTW_B (CVT_B + 8)
#define TOT_B  (ATTW_B + 166)

struct MegaP {
    const float *x, *enc_w, *res_w, *gat_w, *dec_w, *att_src, *att_dst;
    const float *enc_b, *res_b, *gat_b, *dec_b;
    const int* ei;
    unsigned short *xhi, *ewhi, *fwhi, *dwhi;
    unsigned short *xh_b, *resb, *Xhi;
    float *a_src, *a_dst, *biasRG;
    int *row_ptr, *csr, *cnt, *cursor, *bar;
    float* out;
};

// ---------------- P0 unit: cvt / attw+biasRG / edge count (R14 fused0 body) ----------------
__device__ void setup_unit(int bId, int t, const MegaP& p, unsigned short* smem)
{
    if (bId < CVT_B) {
        int iu = bId * 256 + t;
        int i = iu * 8;
        if (i >= C_DW) return;
        const float* src = nullptr; unsigned short* ph; int j, row, c, Kd;
        if (i < C_X)       { j = i;        src = p.x;     ph = p.xhi;
                             row = j >> 8; c = j & 255; Kd = 256; }
        else if (i < C_EW) { j = i - C_X;  src = p.enc_w; ph = p.ewhi;
                             row = j >> 8; c = j & 255; Kd = 256; }
        else if (i < C_FW) { j = i - C_EW; ph = p.fwhi;
                             row = j >> 7; c = j & 127; Kd = 128; }
        else               { j = i - C_FW; src = p.dec_w; ph = p.dwhi;
                             row = j >> 7; c = j & 127; Kd = 128; }
        float4 v0, v1;
        if (src) { v0 = *(const float4*)(src + j); v1 = *(const float4*)(src + j + 4); }
        else {
            const float* s2 = (j < 65536) ? (p.gat_w + j) : (p.res_w + j - 65536);
            v0 = *(const float4*)s2; v1 = *(const float4*)(s2 + 4);
        }
        float vv[8] = {v0.x, v0.y, v0.z, v0.w, v1.x, v1.y, v1.z, v1.w};
        unsigned short hs[8];
#pragma unroll
        for (int k = 0; k < 8; ++k) hs[k] = f2bf(vv[k]);
        int outp = row * Kd + swz(row, c);
        *(u16x8*)(ph + outp) = *(u16x8*)hs;
    } else if (bId < ATTW_B) {
        __syncthreads();                     // prior unit's LDS readers done
        float* sm = (float*)smem;
        int b = bId - CVT_B;            // 0..7
        int is_dst = b >> 2, h = b & 3;
        const float* att = is_dst ? p.att_dst : p.att_src;
        int k = t & 127, half = t >> 7;
        float s = 0.0f;
#pragma unroll 4
        for (int c = half * 64; c < half * 64 + 64; ++c)
            s = fmaf(p.gat_w[(size_t)(h * 128 + c) * 128 + k], att[h * 128 + c], s);
        sm[t] = s;
        __syncthreads();
        if (t < 128) {
            float v = sm[t] + sm[t + 128];
            int R = 1024 + is_dst * 4 + h;
            p.fwhi[(size_t)R * 128 + swz(R, k)] = f2bf(v);
        }
        for (int i = b * 896 + t; i < (b + 1) * 896; i += 256)
            p.fwhi[1032 * 128 + i] = 0;
        if (b < 2) {
            int c = b * 256 + t;
            p.biasRG[c] = p.res_b[c] + p.gat_b[c];
        }
        __syncthreads();                     // drain before block reuses smem
    } else {
        for (int e = (bId - ATTW_B) * 256 + t; e < EP; e += (TOT_B - ATTW_B) * 256) {
            int d = (e < EE) ? p.ei[EE + e] : (e - EE);
            atomicAdd(&p.cnt[d], 1);
        }
    }
}

// ---------------- CSR scan (one unit) / fill units ----------------
__device__ void scan_fn(int tid, const int* cnt, int* row_ptr, unsigned short* smem)
{
    __syncthreads();
    int* smi = (int*)smem;
    int i0 = tid * 40, i1 = min(i0 + 40, NN);
    int part = 0;
    for (int i = i0; i < i1; ++i) part += cnt[i];
    smi[tid] = part;
    __syncthreads();
    for (int off = 1; off < 256; off <<= 1) {
        int v = (tid >= off) ? smi[tid - off] : 0;
        __syncthreads();
        smi[tid] += v;
        __syncthreads();
    }
    int run = smi[tid] - part;
    for (int i = i0; i < i1; ++i) { row_ptr[i] = run; run += cnt[i]; }
    if (tid == 255) row_ptr[NN] = run;
    __syncthreads();
}

__device__ void fill_fn(int f, int tid, const int* ei, const int* row_ptr,
                        int* cursor, int* csr)
{
#pragma unroll
    for (int k = 0; k < 4; ++k) {
        int e = f * 1024 + k * 256 + tid;
        if (e < EP) {
            int s, d;
            if (e < EE) { s = ei[e]; d = ei[EE + e]; } else { s = e - EE; d = s; }
            int pos = row_ptr[d] + atomicAdd(&cursor[d], 1);
            csr[pos] = s;
        }
    }
}

// ---------------- bf16 MFMA GEMM tile (R14 body, 32 KB LDS) ----------------
// MODE 0: dec  -> outF[row*40+col]+bias (scalar, 40 cols)
// MODE 1: enc  -> relu(v+bias) -> bf16 (swizzled), ld=128
// MODE 2: layer-> bn<512: bf16 xh (natural, outH); 512..1023: bf16 res+biasRG (outL);
//                 1024..1031: a_src/a_dst fp32
template<int MODE, int KTILES>
__device__ void gemm_tile(int bm, int bn, int tid,
                          const unsigned short* A, const unsigned short* B,
                          const float* bias, float* outF,
                          unsigned short* outH, unsigned short* outL,
                          float* a_src, float* a_dst, int M, unsigned short* smem)
{
    constexpr int K = KTILES * 128;
    unsigned short* sA = smem;
    unsigned short* sB = smem + 8192;

    const int lane = tid & 63, wv = tid >> 6;
    const int wr = (wv >> 1) * 32, wc = (wv & 1) * 32;
    const int r16 = lane & 15, q4 = lane >> 4;

    f4 acc[2][2];
#pragma unroll
    for (int i = 0; i < 2; ++i)
#pragma unroll
        for (int j = 0; j < 2; ++j) acc[i][j] = (f4){0.f, 0.f, 0.f, 0.f};

    const int ra0 = wr + r16;
    const int rb0 = wc + r16;

    __syncthreads();                       // prior unit's LDS readers done
    for (int kt = 0; kt < KTILES; ++kt) {
        if (kt) __syncthreads();
#pragma unroll
        for (int j = 0; j < 4; ++j) {
            int i = tid + j * 256;                    // unit 0..1023
            int row = i >> 4, u = i & 15;
            int arow = min(bm + row, M - 1);
            size_t ga = (size_t)arow * K + kt * 128 + u * 8;
            size_t gb = (size_t)(bn + row) * K + kt * 128 + u * 8;
            int lb = (wv * 64 + j * 256) * 8;         // wave-uniform LDS base
            gl_lds16(A + ga, sA + lb);
            gl_lds16(B + gb, sB + lb);
        }
        __syncthreads();

#pragma unroll
        for (int ks = 0; ks < 4; ++ks) {
            int u = ks * 4 + q4;
            int oa0 = ra0 * 128 + ((u ^ (ra0 & 7)) * 8);
            int ob0 = rb0 * 128 + ((u ^ (rb0 & 7)) * 8);
            int oa1 = oa0 + 16 * 128;
            int ob1 = ob0 + 16 * 128;
            bf8 A0 = *(const bf8*)(sA + oa0);
            bf8 A1 = *(const bf8*)(sA + oa1);
            bf8 B0 = *(const bf8*)(sB + ob0);
            bf8 B1 = *(const bf8*)(sB + ob1);

            acc[0][0] = __builtin_amdgcn_mfma_f32_16x16x32_bf16(A0, B0, acc[0][0], 0, 0, 0);
            acc[0][1] = __builtin_amdgcn_mfma_f32_16x16x32_bf16(A0, B1, acc[0][1], 0, 0, 0);
            acc[1][0] = __builtin_amdgcn_mfma_f32_16x16x32_bf16(A1, B0, acc[1][0], 0, 0, 0);
            acc[1][1] = __builtin_amdgcn_mfma_f32_16x16x32_bf16(A1, B1, acc[1][1], 0, 0, 0);
        }
    }

    const int rbase = q4 * 4;

    if (MODE == 0 || (MODE == 2 && bn >= 1024)) {
        // scalar epilogue: dec (40 cols) / attn columns (8 cols) — block-uniform branch
#pragma unroll
        for (int i = 0; i < 2; ++i)
#pragma unroll
            for (int j = 0; j < 2; ++j)
#pragma unroll
                for (int r = 0; r < 4; ++r) {
                    int row = bm + wr + i * 16 + rbase + r;
                    int col = bn + wc + j * 16 + r16;
                    if (row >= M) continue;
                    float v = acc[i][j][r];
                    if (MODE == 0) {
                        if (col < NCLASS)
                            outF[(size_t)row * NCLASS + col] = v + bias[col];
                    } else {
                        if (col < 1032) {
                            int h = col - 1024;
                            if (h < 4) a_src[row * 4 + h] = v;
                            else       a_dst[row * 4 + h - 4] = v;
                        }
                    }
                }
        return;
    }

    // ---- staged coalesced epilogue ----
    __syncthreads();
    float* sC = (float*)smem;                 // 64 x 65 fp32 (16.6 KB <= 32 KB)
#pragma unroll
    for (int i = 0; i < 2; ++i)
#pragma unroll
        for (int j = 0; j < 2; ++j)
#pragma unroll
            for (int r = 0; r < 4; ++r)
                sC[(wr + i * 16 + rbase + r) * 65 + (wc + j * 16 + r16)] = acc[i][j][r];
    __syncthreads();

    int row = tid >> 2, seg = tid & 3, c0 = seg * 16;
    int grow = bm + row;
    if (grow < M) {
        float v[16];
#pragma unroll
        for (int k = 0; k < 16; ++k) v[k] = sC[row * 65 + c0 + k];

        if (MODE == 1) {
            unsigned short hs[16];
#pragma unroll
            for (int k = 0; k < 16; ++k)
                hs[k] = f2bf(fmaxf(v[k] + bias[bn + c0 + k], 0.0f));
#pragma unroll
            for (int uu = 0; uu < 2; ++uu) {
                int ug = (bn + c0) / 8 + uu;
                int pu = ug ^ (grow & 7);
                *(u16x8*)(outH + (size_t)grow * 128 + pu * 8) = *(u16x8*)(hs + uu * 8);
            }
        } else {                              // MODE 2, bn < 1024
            if (bn < 512) {                   // xh -> bf16 (natural)
                unsigned short hs[16];
#pragma unroll
                for (int k = 0; k < 16; ++k) hs[k] = f2bf(v[k]);
                *(u16x8*)(outH + (size_t)grow * 512 + bn + c0)     = *(u16x8*)hs;
                *(u16x8*)(outH + (size_t)grow * 512 + bn + c0 + 8) = *(u16x8*)(hs + 8);
            } else {                          // res + (res_b+gat_b) -> bf16 (natural)
                unsigned short hs[16];
#pragma unroll
                for (int k = 0; k < 16; ++k) hs[k] = f2bf(v[k] + bias[bn - 512 + c0 + k]);
                *(u16x8*)(outL + (size_t)grow * 512 + (bn - 512) + c0)     = *(u16x8*)hs;
                *(u16x8*)(outL + (size_t)grow * 512 + (bn - 512) + c0 + 8) = *(u16x8*)(hs + 8);
            }
        }
    }
}

// ------- head-partitioned softmax+gather+residual+ELU+head-mean (R14 body, no LDS) ---------
__device__ void agg_unit(int u, int t, const MegaP& p)
{
    int h  = u / 2500;
    int ng = u - h * 2500;
    int wv = t >> 6, lane = t & 63;
    int d = ng * 4 + wv;                      // 2500*4 = NN exact
    int beg = p.row_ptr[d], end = p.row_ptr[d + 1];
    int eg = lane >> 4, c16 = lane & 15;      // edge subgroup / col lane
    int cb = h * 128 + c16 * 8;               // 8 cols of head h
    float ad = p.a_dst[d * 4 + h];
    u16x8 rv = *(const u16x8*)(p.resb + (size_t)d * HF + cb);

    float acc[8];
#pragma unroll
    for (int k = 0; k < 8; ++k) acc[k] = 0.0f;
    float ssum = 0.0f;

    int e = beg;
    for (; e + 16 <= end; e += 16) {          // 4 chunks x 4 edges in flight
        int sv[4]; float w[4]; u16x8 v[4];
#pragma unroll
        for (int q = 0; q < 4; ++q) sv[q] = p.csr[e + q * 4 + eg];
#pragma unroll
        for (int q = 0; q < 4; ++q) v[q] = *(const u16x8*)(p.xh_b + (size_t)sv[q] * HF + cb);
#pragma unroll
        for (int q = 0; q < 4; ++q) {
            w[q] = __expf(leaky02(p.a_src[sv[q] * 4 + h] + ad));
            ssum += w[q];
        }
#pragma unroll
        for (int q = 0; q < 4; ++q)
#pragma unroll
            for (int k = 0; k < 8; ++k) acc[k] = fmaf(w[q], bf2f(v[q][k]), acc[k]);
    }
    for (; e + 4 <= end; e += 4) {
        int s = p.csr[e + eg];
        u16x8 v = *(const u16x8*)(p.xh_b + (size_t)s * HF + cb);
        float w = __expf(leaky02(p.a_src[s * 4 + h] + ad));
        ssum += w;
#pragma unroll
        for (int k = 0; k < 8; ++k) acc[k] = fmaf(w, bf2f(v[k]), acc[k]);
    }
    if (e + eg < end) {                       // predicated tail (<4 edges)
        int s = p.csr[e + eg];
        u16x8 v = *(const u16x8*)(p.xh_b + (size_t)s * HF + cb);
        float w = __expf(leaky02(p.a_src[s * 4 + h] + ad));
        ssum += w;
#pragma unroll
        for (int k = 0; k < 8; ++k) acc[k] = fmaf(w, bf2f(v[k]), acc[k]);
    }

    // combine the 4 edge-subgroups (lanes differing in bits 4..5)
#pragma unroll
    for (int off = 16; off <= 32; off <<= 1) {
        ssum += __shfl_xor(ssum, off);
#pragma unroll
        for (int k = 0; k < 8; ++k) acc[k] += __shfl_xor(acc[k], off);
    }

    float inv = 1.0f / ssum;
    float uv[8];
#pragma unroll
    for (int k = 0; k < 8; ++k) {
        float v = fmaf(acc[k], inv, bf2f(rv[k]));
        uv[k] = (v > 0.0f) ? v : expm1f(v);
    }
    float z0 = (uv[0] + uv[1] + uv[2] + uv[3]) * 0.25f;
    float z1 = (uv[4] + uv[5] + uv[6] + uv[7]) * 0.25f;
    if (eg == 0) {
        int col = h * 32 + c16 * 2;           // z-cols of head h (2 per lane, same unit)
        unsigned short h0b = f2bf(z0), h1b = f2bf(z1);
        size_t idx = (size_t)d * NHID + swz(d, col);
        *(unsigned*)(p.Xhi + idx) = ((unsigned)h1b << 16) | h0b;
    }
}

// ---------------- the persistent mega kernel ----------------
__global__ __launch_bounds__(256, 2)
void mega_k(MegaP p)
{
    __shared__ __align__(16) unsigned short smem[2 * 64 * 128];   // 32 KB
    const int tid = threadIdx.x;
    const int b0 = blockIdx.x;

    // P0: setup (cvt + attw + biasRG + edge count)
    for (int u = b0; u < TOT_B; u += NB)
        setup_unit(u, tid, p, smem);
    grid_sync(p.bar, NB * 1);

    // P1: enc gemm (157 x 2 tiles) + CSR prefix scan (unit 314)
    for (int u = b0; u < 315; u += NB) {
        if (u < 314)
            gemm_tile<1, 2>((u % 157) * 64, (u / 157) * 64, tid,
                            p.xhi, p.ewhi, p.enc_b, nullptr, p.Xhi, nullptr,
                            nullptr, nullptr, NN, smem);
        else
            scan_fn(tid, p.cnt, p.row_ptr, smem);
    }
    grid_sync(p.bar, NB * 2);

    // P2: layer-1 gemm (157 x 17) + fill_csr (167 units)
    for (int u = b0; u < 2669 + 167; u += NB) {
        if (u < 2669)
            gemm_tile<2, 1>((u % 157) * 64, (u / 157) * 64, tid,
                            p.Xhi, p.fwhi, p.biasRG, nullptr, p.xh_b, p.resb,
                            p.a_src, p.a_dst, NN, smem);
        else
            fill_fn(u - 2669, tid, p.ei, p.row_ptr, p.cursor, p.csr);
    }
    grid_sync(p.bar, NB * 3);

    // P3: agg layer 1 (head-major units)
    for (int u = b0; u < 10000; u += NB) agg_unit(u, tid, p);
    grid_sync(p.bar, NB * 4);

    // P4: layer-2 gemm
    for (int u = b0; u < 2669; u += NB)
        gemm_tile<2, 1>((u % 157) * 64, (u / 157) * 64, tid,
                        p.Xhi, p.fwhi, p.biasRG, nullptr, p.xh_b, p.resb,
                        p.a_src, p.a_dst, NN, smem);
    grid_sync(p.bar, NB * 5);

    // P5: agg layer 2
    for (int u = b0; u < 10000; u += NB) agg_unit(u, tid, p);
    grid_sync(p.bar, NB * 6);

    // P6: decoder
    for (int u = b0; u < 157; u += NB)
        gemm_tile<0, 1>(u * 64, 0, tid, p.Xhi, p.dwhi, p.dec_b, p.out,
                        nullptr, nullptr, nullptr, nullptr, NN, smem);
}

// ---------------- launcher ----------------
extern "C" void kernel_launch(void* const* d_in, const int* in_sizes, int n_in,
                              void* d_out, int out_size, void* d_ws, size_t ws_size,
                              hipStream_t stream)
{
    MegaP p;
    p.x       = (const float*)d_in[0];
    p.ei      = (const int*)d_in[1];
    p.enc_w   = (const float*)d_in[2];
    p.enc_b   = (const float*)d_in[3];
    p.res_w   = (const float*)d_in[4];
    p.res_b   = (const float*)d_in[5];
    p.gat_w   = (const float*)d_in[6];
    p.att_src = (const float*)d_in[7];
    p.att_dst = (const float*)d_in[8];
    p.gat_b   = (const float*)d_in[9];
    p.dec_w   = (const float*)d_in[10];
    p.dec_b   = (const float*)d_in[11];
    p.out     = (float*)d_out;

    char* q = (char*)d_ws;
    auto alloc = [&](size_t bytes) -> void* {
        void* r = (void*)q;
        q += (bytes + 255) & ~(size_t)255;
        return r;
    };
    p.a_src  = (float*)alloc(40000 * 4);
    p.a_dst  = (float*)alloc(40000 * 4);
    p.biasRG = (float*)alloc(512 * 4);
    p.xh_b = (unsigned short*)alloc(5120000 * 2);     // [N,512] bf16 (natural)
    p.resb = (unsigned short*)alloc(5120000 * 2);     // [N,512] bf16 (natural)
    p.Xhi  = (unsigned short*)alloc(1280000 * 2);     // [N,128] bf16 (swizzled)
    p.xhi  = (unsigned short*)alloc(2560000 * 2);     // x [N,256] bf16 (swizzled)
    p.ewhi = (unsigned short*)alloc(32768 * 2);       // enc_w bf16 (swizzled)
    p.fwhi = (unsigned short*)alloc(FCOLS * 128 * 2); // [1088,128] bf16 (swizzled)
    p.row_ptr = (int*)alloc(10004 * 4);
    p.csr     = (int*)alloc(170000 * 4);
    // ---- zero zone (single memset): barrier + padded dec W + cnt + cursor ----
    char* zbase = q;
    p.bar  = (int*)alloc(256);
    p.dwhi = (unsigned short*)alloc(8192 * 2);        // [64,128] padded (swizzled)
    p.cnt    = (int*)alloc(10000 * 4);
    p.cursor = (int*)alloc(10000 * 4);
    size_t zbytes = (size_t)(q - zbase);

    hipMemsetAsync(zbase, 0, zbytes, stream);

    mega_k<<<NB, 256, 0, stream>>>(p);
}

// Round 16
// 799.553 us; speedup vs baseline: 1.2722x; 1.2722x over previous
//
#include <hip/hip_runtime.h>
#include <math.h>

#define NN 10000
#define EE 160000
#define EP 170000          // EE + NN self loops
#define NFEAT 256
#define NHID 128
#define NH 4
#define HF 512             // NH * NHID
#define NCLASS 40
#define FCOLS 1088         // 512 xh + 512 res + 8 attn + 56 pad
#define NB 1024            // persistent grid: 4 blocks/CU co-resident

typedef __attribute__((ext_vector_type(8))) short bf8;     // 8 bf16 (4 VGPR) MFMA frag
typedef __attribute__((ext_vector_type(8))) unsigned short u16x8;
typedef __attribute__((ext_vector_type(4))) float f4;

__device__ __forceinline__ float leaky02(float x) { return x >= 0.0f ? x : 0.2f * x; }

__device__ __forceinline__ unsigned short f2bf(float f) {   // RNE
    unsigned u = __builtin_bit_cast(unsigned, f);
    unsigned r = (u + 0x7FFF + ((u >> 16) & 1)) >> 16;
    return (unsigned short)r;
}
__device__ __forceinline__ float bf2f(unsigned short h) {
    return __builtin_bit_cast(float, (unsigned)h << 16);
}

// Bank-swizzled element position within a row of length K (baked into GLOBAL layout
// of MFMA operands so global->LDS staging is a LINEAR copy for global_load_lds).
__device__ __forceinline__ int swz(int row, int c) {
    return ((((c >> 3) ^ (row & 7)) << 3) | (c & 7));
}

// 16B global -> LDS direct DMA
__device__ __forceinline__ void gl_lds16(const unsigned short* g, unsigned short* l)
{
    __builtin_amdgcn_global_load_lds(
        (const __attribute__((address_space(1))) unsigned int*)g,
        (__attribute__((address_space(3))) unsigned int*)l, 16, 0, 0);
}

// Device-scope grid barrier, monotonic counter. R15 lesson: the SPIN must use
// RELAXED loads — an agent-scope ACQUIRE poll invalidates the XCD's L1+L2 every
// iteration (R15: FETCH 2x, HBM 220 GB/s, 5x slowdown). One acquire at exit gives
// the needed cross-XCD visibility.
__device__ __forceinline__ void grid_sync(int* bar, int target)
{
    __syncthreads();
    if (threadIdx.x == 0) {
        __hip_atomic_fetch_add(bar, 1, __ATOMIC_RELEASE, __HIP_MEMORY_SCOPE_AGENT);
        while (__hip_atomic_load(bar, __ATOMIC_RELAXED, __HIP_MEMORY_SCOPE_AGENT) < target)
            __builtin_amdgcn_s_sleep(8);
        (void)__hip_atomic_load(bar, __ATOMIC_ACQUIRE, __HIP_MEMORY_SCOPE_AGENT);
    }
    __syncthreads();
}

#define C_X   2560000
#define C_EW  (C_X + 32768)
#define C_FW  (C_EW + 131072)      // gat_w + res_w -> fw rows 0..1023
#define C_DW  (C_FW + 5120)        // dec_w [40,128]
#define CVT_B  1333                // ceil((C_DW/8)/256)
#define ATTW_B (CVT_B + 8)
#define TOT_B  (ATTW_B + 166)

struct MegaP {
    const float *x, *enc_w, *res_w, *gat_w, *dec_w, *att_src, *att_dst;
    const float *enc_b, *res_b, *gat_b, *dec_b;
    const int* ei;
    unsigned short *xhi, *ewhi, *fwhi, *dwhi;
    unsigned short *xh_b, *resb, *Xhi;
    float *a_src, *a_dst, *biasRG;
    int *row_ptr, *csr, *cnt, *cursor, *bar;
    float* out;
};

// ---------------- P0 unit: cvt / attw+biasRG / edge count ----------------
__device__ void setup_unit(int bId, int t, const MegaP& p, unsigned short* smem)
{
    if (bId < CVT_B) {
        int iu = bId * 256 + t;
        int i = iu * 8;
        if (i >= C_DW) return;
        const float* src = nullptr; unsigned short* ph; int j, row, c, Kd;
        if (i < C_X)       { j = i;        src = p.x;     ph = p.xhi;
                             row = j >> 8; c = j & 255; Kd = 256; }
        else if (i < C_EW) { j = i - C_X;  src = p.enc_w; ph = p.ewhi;
                             row = j >> 8; c = j & 255; Kd = 256; }
        else if (i < C_FW) { j = i - C_EW; ph = p.fwhi;
                             row = j >> 7; c = j & 127; Kd = 128; }
        else               { j = i - C_FW; src = p.dec_w; ph = p.dwhi;
                             row = j >> 7; c = j & 127; Kd = 128; }
        float4 v0, v1;
        if (src) { v0 = *(const float4*)(src + j); v1 = *(const float4*)(src + j + 4); }
        else {
            const float* s2 = (j < 65536) ? (p.gat_w + j) : (p.res_w + j - 65536);
            v0 = *(const float4*)s2; v1 = *(const float4*)(s2 + 4);
        }
        float vv[8] = {v0.x, v0.y, v0.z, v0.w, v1.x, v1.y, v1.z, v1.w};
        unsigned short hs[8];
#pragma unroll
        for (int k = 0; k < 8; ++k) hs[k] = f2bf(vv[k]);
        int outp = row * Kd + swz(row, c);
        *(u16x8*)(ph + outp) = *(u16x8*)hs;
    } else if (bId < ATTW_B) {
        __syncthreads();                     // prior unit's LDS readers done
        float* sm = (float*)smem;
        int b = bId - CVT_B;            // 0..7
        int is_dst = b >> 2, h = b & 3;
        const float* att = is_dst ? p.att_dst : p.att_src;
        int k = t & 127, half = t >> 7;
        float s = 0.0f;
#pragma unroll 4
        for (int c = half * 64; c < half * 64 + 64; ++c)
            s = fmaf(p.gat_w[(size_t)(h * 128 + c) * 128 + k], att[h * 128 + c], s);
        sm[t] = s;
        __syncthreads();
        if (t < 128) {
            float v = sm[t] + sm[t + 128];
            int R = 1024 + is_dst * 4 + h;
            p.fwhi[(size_t)R * 128 + swz(R, k)] = f2bf(v);
        }
        for (int i = b * 896 + t; i < (b + 1) * 896; i += 256)
            p.fwhi[1032 * 128 + i] = 0;
        if (b < 2) {
            int c = b * 256 + t;
            p.biasRG[c] = p.res_b[c] + p.gat_b[c];
        }
        __syncthreads();                     // drain before block reuses smem
    } else {
        for (int e = (bId - ATTW_B) * 256 + t; e < EP; e += (TOT_B - ATTW_B) * 256) {
            int d = (e < EE) ? p.ei[EE + e] : (e - EE);
            atomicAdd(&p.cnt[d], 1);
        }
    }
}

// ---------------- CSR scan (one unit) / fill units ----------------
__device__ void scan_fn(int tid, const int* cnt, int* row_ptr, unsigned short* smem)
{
    __syncthreads();
    int* smi = (int*)smem;
    int i0 = tid * 40, i1 = min(i0 + 40, NN);
    int part = 0;
    for (int i = i0; i < i1; ++i) part += cnt[i];
    smi[tid] = part;
    __syncthreads();
    for (int off = 1; off < 256; off <<= 1) {
        int v = (tid >= off) ? smi[tid - off] : 0;
        __syncthreads();
        smi[tid] += v;
        __syncthreads();
    }
    int run = smi[tid] - part;
    for (int i = i0; i < i1; ++i) { row_ptr[i] = run; run += cnt[i]; }
    if (tid == 255) row_ptr[NN] = run;
    __syncthreads();
}

__device__ void fill_fn(int f, int tid, const int* ei, const int* row_ptr,
                        int* cursor, int* csr)
{
#pragma unroll
    for (int k = 0; k < 4; ++k) {
        int e = f * 1024 + k * 256 + tid;
        if (e < EP) {
            int s, d;
            if (e < EE) { s = ei[e]; d = ei[EE + e]; } else { s = e - EE; d = s; }
            int pos = row_ptr[d] + atomicAdd(&cursor[d], 1);
            csr[pos] = s;
        }
    }
}

// ---------------- bf16 MFMA GEMM tile (R14 body, 32 KB LDS) ----------------
// MODE 0: dec  -> outF[row*40+col]+bias (scalar, 40 cols)
// MODE 1: enc  -> relu(v+bias) -> bf16 (swizzled), ld=128
// MODE 2: layer-> bn<512: bf16 xh (natural, outH); 512..1023: bf16 res+biasRG (outL);
//                 1024..1031: a_src/a_dst fp32
template<int MODE, int KTILES>
__device__ void gemm_tile(int bm, int bn, int tid,
                          const unsigned short* A, const unsigned short* B,
                          const float* bias, float* outF,
                          unsigned short* outH, unsigned short* outL,
                          float* a_src, float* a_dst, int M, unsigned short* smem)
{
    constexpr int K = KTILES * 128;
    unsigned short* sA = smem;
    unsigned short* sB = smem + 8192;

    const int lane = tid & 63, wv = tid >> 6;
    const int wr = (wv >> 1) * 32, wc = (wv & 1) * 32;
    const int r16 = lane & 15, q4 = lane >> 4;

    f4 acc[2][2];
#pragma unroll
    for (int i = 0; i < 2; ++i)
#pragma unroll
        for (int j = 0; j < 2; ++j) acc[i][j] = (f4){0.f, 0.f, 0.f, 0.f};

    const int ra0 = wr + r16;
    const int rb0 = wc + r16;

    __syncthreads();                       // prior unit's LDS readers done
    for (int kt = 0; kt < KTILES; ++kt) {
        if (kt) __syncthreads();
#pragma unroll
        for (int j = 0; j < 4; ++j) {
            int i = tid + j * 256;                    // unit 0..1023
            int row = i >> 4, u = i & 15;
            int arow = min(bm + row, M - 1);
            size_t ga = (size_t)arow * K + kt * 128 + u * 8;
            size_t gb = (size_t)(bn + row) * K + kt * 128 + u * 8;
            int lb = (wv * 64 + j * 256) * 8;         // wave-uniform LDS base
            gl_lds16(A + ga, sA + lb);
            gl_lds16(B + gb, sB + lb);
        }
        __syncthreads();

#pragma unroll
        for (int ks = 0; ks < 4; ++ks) {
            int u = ks * 4 + q4;
            int oa0 = ra0 * 128 + ((u ^ (ra0 & 7)) * 8);
            int ob0 = rb0 * 128 + ((u ^ (rb0 & 7)) * 8);
            int oa1 = oa0 + 16 * 128;
            int ob1 = ob0 + 16 * 128;
            bf8 A0 = *(const bf8*)(sA + oa0);
            bf8 A1 = *(const bf8*)(sA + oa1);
            bf8 B0 = *(const bf8*)(sB + ob0);
            bf8 B1 = *(const bf8*)(sB + ob1);

            acc[0][0] = __builtin_amdgcn_mfma_f32_16x16x32_bf16(A0, B0, acc[0][0], 0, 0, 0);
            acc[0][1] = __builtin_amdgcn_mfma_f32_16x16x32_bf16(A0, B1, acc[0][1], 0, 0, 0);
            acc[1][0] = __builtin_amdgcn_mfma_f32_16x16x32_bf16(A1, B0, acc[1][0], 0, 0, 0);
            acc[1][1] = __builtin_amdgcn_mfma_f32_16x16x32_bf16(A1, B1, acc[1][1], 0, 0, 0);
        }
    }

    const int rbase = q4 * 4;

    if (MODE == 0 || (MODE == 2 && bn >= 1024)) {
        // scalar epilogue: dec (40 cols) / attn columns (8 cols) — block-uniform branch
#pragma unroll
        for (int i = 0; i < 2; ++i)
#pragma unroll
            for (int j = 0; j < 2; ++j)
#pragma unroll
                for (int r = 0; r < 4; ++r) {
                    int row = bm + wr + i * 16 + rbase + r;
                    int col = bn + wc + j * 16 + r16;
                    if (row >= M) continue;
                    float v = acc[i][j][r];
                    if (MODE == 0) {
                        if (col < NCLASS)
                            outF[(size_t)row * NCLASS + col] = v + bias[col];
                    } else {
                        if (col < 1032) {
                            int h = col - 1024;
                            if (h < 4) a_src[row * 4 + h] = v;
                            else       a_dst[row * 4 + h - 4] = v;
                        }
                    }
                }
        return;
    }

    // ---- staged coalesced epilogue ----
    __syncthreads();
    float* sC = (float*)smem;                 // 64 x 65 fp32 (16.6 KB <= 32 KB)
#pragma unroll
    for (int i = 0; i < 2; ++i)
#pragma unroll
        for (int j = 0; j < 2; ++j)
#pragma unroll
            for (int r = 0; r < 4; ++r)
                sC[(wr + i * 16 + rbase + r) * 65 + (wc + j * 16 + r16)] = acc[i][j][r];
    __syncthreads();

    int row = tid >> 2, seg = tid & 3, c0 = seg * 16;
    int grow = bm + row;
    if (grow < M) {
        float v[16];
#pragma unroll
        for (int k = 0; k < 16; ++k) v[k] = sC[row * 65 + c0 + k];

        if (MODE == 1) {
            unsigned short hs[16];
#pragma unroll
            for (int k = 0; k < 16; ++k)
                hs[k] = f2bf(fmaxf(v[k] + bias[bn + c0 + k], 0.0f));
#pragma unroll
            for (int uu = 0; uu < 2; ++uu) {
                int ug = (bn + c0) / 8 + uu;
                int pu = ug ^ (grow & 7);
                *(u16x8*)(outH + (size_t)grow * 128 + pu * 8) = *(u16x8*)(hs + uu * 8);
            }
        } else {                              // MODE 2, bn < 1024
            if (bn < 512) {                   // xh -> bf16 (natural)
                unsigned short hs[16];
#pragma unroll
                for (int k = 0; k < 16; ++k) hs[k] = f2bf(v[k]);
                *(u16x8*)(outH + (size_t)grow * 512 + bn + c0)     = *(u16x8*)hs;
                *(u16x8*)(outH + (size_t)grow * 512 + bn + c0 + 8) = *(u16x8*)(hs + 8);
            } else {                          // res + (res_b+gat_b) -> bf16 (natural)
                unsigned short hs[16];
#pragma unroll
                for (int k = 0; k < 16; ++k) hs[k] = f2bf(v[k] + bias[bn - 512 + c0 + k]);
                *(u16x8*)(outL + (size_t)grow * 512 + (bn - 512) + c0)     = *(u16x8*)hs;
                *(u16x8*)(outL + (size_t)grow * 512 + (bn - 512) + c0 + 8) = *(u16x8*)(hs + 8);
            }
        }
    }
}

// ------- head-partitioned softmax+gather+residual+ELU+head-mean (R14 body, no LDS) ---------
__device__ void agg_unit(int u, int t, const MegaP& p)
{
    int h  = u / 2500;
    int ng = u - h * 2500;
    int wv = t >> 6, lane = t & 63;
    int d = ng * 4 + wv;                      // 2500*4 = NN exact
    int beg = p.row_ptr[d], end = p.row_ptr[d + 1];
    int eg = lane >> 4, c16 = lane & 15;      // edge subgroup / col lane
    int cb = h * 128 + c16 * 8;               // 8 cols of head h
    float ad = p.a_dst[d * 4 + h];
    u16x8 rv = *(const u16x8*)(p.resb + (size_t)d * HF + cb);

    float acc[8];
#pragma unroll
    for (int k = 0; k < 8; ++k) acc[k] = 0.0f;
    float ssum = 0.0f;

    int e = beg;
    for (; e + 16 <= end; e += 16) {          // 4 chunks x 4 edges in flight
        int sv[4]; float w[4]; u16x8 v[4];
#pragma unroll
        for (int q = 0; q < 4; ++q) sv[q] = p.csr[e + q * 4 + eg];
#pragma unroll
        for (int q = 0; q < 4; ++q) v[q] = *(const u16x8*)(p.xh_b + (size_t)sv[q] * HF + cb);
#pragma unroll
        for (int q = 0; q < 4; ++q) {
            w[q] = __expf(leaky02(p.a_src[sv[q] * 4 + h] + ad));
            ssum += w[q];
        }
#pragma unroll
        for (int q = 0; q < 4; ++q)
#pragma unroll
            for (int k = 0; k < 8; ++k) acc[k] = fmaf(w[q], bf2f(v[q][k]), acc[k]);
    }
    for (; e + 4 <= end; e += 4) {
        int s = p.csr[e + eg];
        u16x8 v = *(const u16x8*)(p.xh_b + (size_t)s * HF + cb);
        float w = __expf(leaky02(p.a_src[s * 4 + h] + ad));
        ssum += w;
#pragma unroll
        for (int k = 0; k < 8; ++k) acc[k] = fmaf(w, bf2f(v[k]), acc[k]);
    }
    if (e + eg < end) {                       // predicated tail (<4 edges)
        int s = p.csr[e + eg];
        u16x8 v = *(const u16x8*)(p.xh_b + (size_t)s * HF + cb);
        float w = __expf(leaky02(p.a_src[s * 4 + h] + ad));
        ssum += w;
#pragma unroll
        for (int k = 0; k < 8; ++k) acc[k] = fmaf(w, bf2f(v[k]), acc[k]);
    }

    // combine the 4 edge-subgroups (lanes differing in bits 4..5)
#pragma unroll
    for (int off = 16; off <= 32; off <<= 1) {
        ssum += __shfl_xor(ssum, off);
#pragma unroll
        for (int k = 0; k < 8; ++k) acc[k] += __shfl_xor(acc[k], off);
    }

    float inv = 1.0f / ssum;
    float uv[8];
#pragma unroll
    for (int k = 0; k < 8; ++k) {
        float v = fmaf(acc[k], inv, bf2f(rv[k]));
        uv[k] = (v > 0.0f) ? v : expm1f(v);
    }
    float z0 = (uv[0] + uv[1] + uv[2] + uv[3]) * 0.25f;
    float z1 = (uv[4] + uv[5] + uv[6] + uv[7]) * 0.25f;
    if (eg == 0) {
        int col = h * 32 + c16 * 2;           // z-cols of head h (2 per lane, same unit)
        unsigned short h0b = f2bf(z0), h1b = f2bf(z1);
        size_t idx = (size_t)d * NHID + swz(d, col);
        *(unsigned*)(p.Xhi + idx) = ((unsigned)h1b << 16) | h0b;
    }
}

// ---------------- the persistent mega kernel ----------------
__global__ __launch_bounds__(256, 4)
void mega_k(MegaP p)
{
    __shared__ __align__(16) unsigned short smem[2 * 64 * 128];   // 32 KB
    const int tid = threadIdx.x;
    const int b0 = blockIdx.x;

    // P0: setup (cvt + attw + biasRG + edge count)
    for (int u = b0; u < TOT_B; u += NB)
        setup_unit(u, tid, p, smem);
    grid_sync(p.bar, NB * 1);

    // P1: enc gemm (157 x 2 tiles) + CSR prefix scan (unit 314)
    for (int u = b0; u < 315; u += NB) {
        if (u < 314)
            gemm_tile<1, 2>((u % 157) * 64, (u / 157) * 64, tid,
                            p.xhi, p.ewhi, p.enc_b, nullptr, p.Xhi, nullptr,
                            nullptr, nullptr, NN, smem);
        else
            scan_fn(tid, p.cnt, p.row_ptr, smem);
    }
    grid_sync(p.bar, NB * 2);

    // P2: layer-1 gemm (157 x 17) + fill_csr (167 units)
    for (int u = b0; u < 2669 + 167; u += NB) {
        if (u < 2669)
            gemm_tile<2, 1>((u % 157) * 64, (u / 157) * 64, tid,
                            p.Xhi, p.fwhi, p.biasRG, nullptr, p.xh_b, p.resb,
                            p.a_src, p.a_dst, NN, smem);
        else
            fill_fn(u - 2669, tid, p.ei, p.row_ptr, p.cursor, p.csr);
    }
    grid_sync(p.bar, NB * 3);

    // P3: agg layer 1 (head-major units)
    for (int u = b0; u < 10000; u += NB) agg_unit(u, tid, p);
    grid_sync(p.bar, NB * 4);

    // P4: layer-2 gemm
    for (int u = b0; u < 2669; u += NB)
        gemm_tile<2, 1>((u % 157) * 64, (u / 157) * 64, tid,
                        p.Xhi, p.fwhi, p.biasRG, nullptr, p.xh_b, p.resb,
                        p.a_src, p.a_dst, NN, smem);
    grid_sync(p.bar, NB * 5);

    // P5: agg layer 2
    for (int u = b0; u < 10000; u += NB) agg_unit(u, tid, p);
    grid_sync(p.bar, NB * 6);

    // P6: decoder
    for (int u = b0; u < 157; u += NB)
        gemm_tile<0, 1>(u * 64, 0, tid, p.Xhi, p.dwhi, p.dec_b, p.out,
                        nullptr, nullptr, nullptr, nullptr, NN, smem);
}

// ---------------- launcher ----------------
extern "C" void kernel_launch(void* const* d_in, const int* in_sizes, int n_in,
                              void* d_out, int out_size, void* d_ws, size_t ws_size,
                              hipStream_t stream)
{
    MegaP p;
    p.x       = (const float*)d_in[0];
    p.ei      = (const int*)d_in[1];
    p.enc_w   = (const float*)d_in[2];
    p.enc_b   = (const float*)d_in[3];
    p.res_w   = (const float*)d_in[4];
    p.res_b   = (const float*)d_in[5];
    p.gat_w   = (const float*)d_in[6];
    p.att_src = (const float*)d_in[7];
    p.att_dst = (const float*)d_in[8];
    p.gat_b   = (const float*)d_in[9];
    p.dec_w   = (const float*)d_in[10];
    p.dec_b   = (const float*)d_in[11];
    p.out     = (float*)d_out;

    char* q = (char*)d_ws;
    auto alloc = [&](size_t bytes) -> void* {
        void* r = (void*)q;
        q += (bytes + 255) & ~(size_t)255;
        return r;
    };
    p.a_src  = (float*)alloc(40000 * 4);
    p.a_dst  = (float*)alloc(40000 * 4);
    p.biasRG = (float*)alloc(512 * 4);
    p.xh_b = (unsigned short*)alloc(5120000 * 2);     // [N,512] bf16 (natural)
    p.resb = (unsigned short*)alloc(5120000 * 2);     // [N,512] bf16 (natural)
    p.Xhi  = (unsigned short*)alloc(1280000 * 2);     // [N,128] bf16 (swizzled)
    p.xhi  = (unsigned short*)alloc(2560000 * 2);     // x [N,256] bf16 (swizzled)
    p.ewhi = (unsigned short*)alloc(32768 * 2);       // enc_w bf16 (swizzled)
    p.fwhi = (unsigned short*)alloc(FCOLS * 128 * 2); // [1088,128] bf16 (swizzled)
    p.row_ptr = (int*)alloc(10004 * 4);
    p.csr     = (int*)alloc(170000 * 4);
    // ---- zero zone (single memset): barrier + padded dec W + cnt + cursor ----
    char* zbase = q;
    p.bar  = (int*)alloc(256);
    p.dwhi = (unsigned short*)alloc(8192 * 2);        // [64,128] padded (swizzled)
    p.cnt    = (int*)alloc(10000 * 4);
    p.cursor = (int*)alloc(10000 * 4);
    size_t zbytes = (size_t)(q - zbase);

    hipMemsetAsync(zbase, 0, zbytes, stream);

    mega_k<<<NB, 256, 0, stream>>>(p);
}

// Round 17
// 226.713 us; speedup vs baseline: 4.4868x; 3.5267x over previous
//
#include <hip/hip_runtime.h>
#include <math.h>

#define NN 10000
#define EE 160000
#define EP 170000          // EE + NN self loops
#define NFEAT 256
#define NHID 128
#define NH 4
#define HF 512             // NH * NHID
#define NCLASS 40
#define FCOLS 1088         // 512 xh + 512 res + 8 attn + 56 pad

typedef __attribute__((ext_vector_type(8))) short bf8;     // 8 bf16 (4 VGPR) MFMA frag
typedef __attribute__((ext_vector_type(8))) unsigned short u16x8;
typedef __attribute__((ext_vector_type(4))) float f4;

__device__ __forceinline__ float leaky02(float x) { return x >= 0.0f ? x : 0.2f * x; }

__device__ __forceinline__ unsigned short f2bf(float f) {   // RNE
    unsigned u = __builtin_bit_cast(unsigned, f);
    unsigned r = (u + 0x7FFF + ((u >> 16) & 1)) >> 16;
    return (unsigned short)r;
}
__device__ __forceinline__ float bf2f(unsigned short h) {
    return __builtin_bit_cast(float, (unsigned)h << 16);
}

// Bank-swizzled element position within a row of length K (baked into GLOBAL layout
// of MFMA operands so global->LDS staging is a LINEAR copy for global_load_lds).
__device__ __forceinline__ int swz(int row, int c) {
    return ((((c >> 3) ^ (row & 7)) << 3) | (c & 7));
}

// 16B global -> LDS direct DMA
__device__ __forceinline__ void gl_lds16(const unsigned short* g, unsigned short* l)
{
    __builtin_amdgcn_global_load_lds(
        (const __attribute__((address_space(1))) unsigned int*)g,
        (__attribute__((address_space(3))) unsigned int*)l, 16, 0, 0);
}

// ---------------- fused setup: cvt (bf16, swizzled) + attw + biasRG + edge count ----------
#define C_X   2560000
#define C_EW  (C_X + 32768)
#define C_FW  (C_EW + 131072)      // gat_w + res_w -> fw rows 0..1023
#define C_DW  (C_FW + 5120)        // dec_w [40,128]
#define CVT_B  1333                // ceil((C_DW/8)/256)
#define ATTW_B (CVT_B + 8)
#define TOT_B  (ATTW_B + 166)

__global__ __launch_bounds__(256)
void fused0_k(const float* __restrict__ x, const float* __restrict__ enc_w,
              const float* __restrict__ gat_w, const float* __restrict__ res_w,
              const float* __restrict__ dec_w,
              const float* __restrict__ att_src, const float* __restrict__ att_dst,
              const float* __restrict__ res_b, const float* __restrict__ gat_b,
              const int* __restrict__ ei,
              unsigned short* __restrict__ xhi, unsigned short* __restrict__ ewhi,
              unsigned short* __restrict__ fwhi, unsigned short* __restrict__ dwhi,
              float* __restrict__ biasRG, int* __restrict__ cnt)
{
    int bId = blockIdx.x;
    int t = threadIdx.x;
    if (bId < CVT_B) {
        int iu = bId * 256 + t;
        int i = iu * 8;
        if (i >= C_DW) return;
        const float* src = nullptr; unsigned short* ph; int j, row, c, Kd;
        if (i < C_X)       { j = i;        src = x;     ph = xhi;
                             row = j >> 8; c = j & 255; Kd = 256; }
        else if (i < C_EW) { j = i - C_X;  src = enc_w; ph = ewhi;
                             row = j >> 8; c = j & 255; Kd = 256; }
        else if (i < C_FW) { j = i - C_EW; ph = fwhi;
                             row = j >> 7; c = j & 127; Kd = 128; }
        else               { j = i - C_FW; src = dec_w; ph = dwhi;
                             row = j >> 7; c = j & 127; Kd = 128; }
        float4 v0, v1;
        if (src) { v0 = *(const float4*)(src + j); v1 = *(const float4*)(src + j + 4); }
        else {
            const float* s2 = (j < 65536) ? (gat_w + j) : (res_w + j - 65536);
            v0 = *(const float4*)s2; v1 = *(const float4*)(s2 + 4);
        }
        float vv[8] = {v0.x, v0.y, v0.z, v0.w, v1.x, v1.y, v1.z, v1.w};
        unsigned short hs[8];
#pragma unroll
        for (int k = 0; k < 8; ++k) hs[k] = f2bf(vv[k]);
        int outp = row * Kd + swz(row, c);
        *(u16x8*)(ph + outp) = *(u16x8*)hs;
    } else if (bId < ATTW_B) {
        __shared__ float sm[256];
        int b = bId - CVT_B;            // 0..7
        int is_dst = b >> 2, h = b & 3;
        const float* att = is_dst ? att_dst : att_src;
        int k = t & 127, half = t >> 7;
        float s = 0.0f;
#pragma unroll 4
        for (int c = half * 64; c < half * 64 + 64; ++c)
            s = fmaf(gat_w[(size_t)(h * 128 + c) * 128 + k], att[h * 128 + c], s);
        sm[t] = s;
        __syncthreads();
        if (t < 128) {
            float v = sm[t] + sm[t + 128];
            int R = 1024 + is_dst * 4 + h;
            fwhi[(size_t)R * 128 + swz(R, k)] = f2bf(v);
        }
        for (int i = b * 896 + t; i < (b + 1) * 896; i += 256)
            fwhi[1032 * 128 + i] = 0;
        if (b < 2) {
            int c = b * 256 + t;
            biasRG[c] = res_b[c] + gat_b[c];
        }
    } else {
        for (int e = (bId - ATTW_B) * 256 + t; e < EP; e += (TOT_B - ATTW_B) * 256) {
            int d = (e < EE) ? ei[EE + e] : (e - EE);
            atomicAdd(&cnt[d], 1);
        }
    }
}

// ---------------- bf16 MFMA GEMM (32 KB LDS) + LDS-staged epilogue ----------------
// Block 64x64, 4 waves 2x2, wave 32x32 = 2x2 MFMA tiles. acc += A*B (plain bf16).
// MODE 0: dec  -> outF[row*40+col]+bias (scalar, 40 cols)
// MODE 1: enc  -> relu(v+bias) -> bf16 (swizzled), ld=128
// MODE 2: layer-> bn<512: bf16 xh (natural, outH); 512..1023: bf16 res+biasRG (outL);
//                 1024..1031: a_src/a_dst fp32
// MERGE 1: last y-slice, x==0 runs the CSR prefix scan; MERGE 2: last y-slice fills CSR.
template<int MODE, int KTILES, int MERGE>
__global__ __launch_bounds__(256)
void gemm3_k(const unsigned short* __restrict__ A, const unsigned short* __restrict__ B,
             const float* __restrict__ bias, float* __restrict__ outF,
             unsigned short* __restrict__ outH, unsigned short* __restrict__ outL,
             float* __restrict__ a_src, float* __restrict__ a_dst, int M,
             const int* __restrict__ ei, const int* __restrict__ cnt,
             int* __restrict__ row_ptr, int* __restrict__ cursor, int* __restrict__ csr)
{
    constexpr int K = KTILES * 128;
    __shared__ __align__(16) unsigned short smem[2 * 64 * 128];   // 32 KB
    const int tid = threadIdx.x;

    if (MERGE && blockIdx.y == gridDim.y - 1) {
        if (MERGE == 1) {
            if (blockIdx.x != 0) return;
            int* smi = (int*)smem;
            int i0 = tid * 40, i1 = min(i0 + 40, NN);
            int part = 0;
            for (int i = i0; i < i1; ++i) part += cnt[i];
            smi[tid] = part;
            __syncthreads();
            for (int off = 1; off < 256; off <<= 1) {
                int v = (tid >= off) ? smi[tid - off] : 0;
                __syncthreads();
                smi[tid] += v;
                __syncthreads();
            }
            int run = smi[tid] - part;
            for (int i = i0; i < i1; ++i) { row_ptr[i] = run; run += cnt[i]; }
            if (tid == 255) row_ptr[NN] = run;
        } else {
            int stride = gridDim.x * 256;
            for (int e = blockIdx.x * 256 + tid; e < EP; e += stride) {
                int s, d;
                if (e < EE) { s = ei[e]; d = ei[EE + e]; } else { s = e - EE; d = s; }
                int pos = row_ptr[d] + atomicAdd(&cursor[d], 1);
                csr[pos] = s;
            }
        }
        return;
    }

    unsigned short* sA = smem;
    unsigned short* sB = smem + 8192;

    const int lane = tid & 63, wv = tid >> 6;
    const int wr = (wv >> 1) * 32, wc = (wv & 1) * 32;
    const int bm = blockIdx.x * 64, bn = blockIdx.y * 64;
    const int r16 = lane & 15, q4 = lane >> 4;

    f4 acc[2][2];
#pragma unroll
    for (int i = 0; i < 2; ++i)
#pragma unroll
        for (int j = 0; j < 2; ++j) acc[i][j] = (f4){0.f, 0.f, 0.f, 0.f};

    const int ra0 = wr + r16;
    const int rb0 = wc + r16;

    for (int kt = 0; kt < KTILES; ++kt) {
        if (kt) __syncthreads();
#pragma unroll
        for (int j = 0; j < 4; ++j) {
            int i = tid + j * 256;                    // unit 0..1023
            int row = i >> 4, u = i & 15;
            int arow = min(bm + row, M - 1);
            size_t ga = (size_t)arow * K + kt * 128 + u * 8;
            size_t gb = (size_t)(bn + row) * K + kt * 128 + u * 8;
            int lb = (wv * 64 + j * 256) * 8;         // wave-uniform LDS base
            gl_lds16(A + ga, sA + lb);
            gl_lds16(B + gb, sB + lb);
        }
        __syncthreads();

#pragma unroll
        for (int ks = 0; ks < 4; ++ks) {
            int u = ks * 4 + q4;
            int oa0 = ra0 * 128 + ((u ^ (ra0 & 7)) * 8);
            int ob0 = rb0 * 128 + ((u ^ (rb0 & 7)) * 8);
            int oa1 = oa0 + 16 * 128;
            int ob1 = ob0 + 16 * 128;
            bf8 A0 = *(const bf8*)(sA + oa0);
            bf8 A1 = *(const bf8*)(sA + oa1);
            bf8 B0 = *(const bf8*)(sB + ob0);
            bf8 B1 = *(const bf8*)(sB + ob1);

            acc[0][0] = __builtin_amdgcn_mfma_f32_16x16x32_bf16(A0, B0, acc[0][0], 0, 0, 0);
            acc[0][1] = __builtin_amdgcn_mfma_f32_16x16x32_bf16(A0, B1, acc[0][1], 0, 0, 0);
            acc[1][0] = __builtin_amdgcn_mfma_f32_16x16x32_bf16(A1, B0, acc[1][0], 0, 0, 0);
            acc[1][1] = __builtin_amdgcn_mfma_f32_16x16x32_bf16(A1, B1, acc[1][1], 0, 0, 0);
        }
    }

    const int rbase = q4 * 4;

    if (MODE == 0 || (MODE == 2 && bn >= 1024)) {
        // scalar epilogue: dec (40 cols) / attn columns (8 cols)
#pragma unroll
        for (int i = 0; i < 2; ++i)
#pragma unroll
            for (int j = 0; j < 2; ++j)
#pragma unroll
                for (int r = 0; r < 4; ++r) {
                    int row = bm + wr + i * 16 + rbase + r;
                    int col = bn + wc + j * 16 + r16;
                    if (row >= M) continue;
                    float v = acc[i][j][r];
                    if (MODE == 0) {
                        if (col < NCLASS)
                            outF[(size_t)row * NCLASS + col] = v + bias[col];
                    } else {
                        if (col < 1032) {
                            int h = col - 1024;
                            if (h < 4) a_src[row * 4 + h] = v;
                            else       a_dst[row * 4 + h - 4] = v;
                        }
                    }
                }
        return;
    }

    // ---- staged coalesced epilogue ----
    __syncthreads();
    float* sC = (float*)smem;                 // 64 x 65 fp32 (16.6 KB <= 32 KB)
#pragma unroll
    for (int i = 0; i < 2; ++i)
#pragma unroll
        for (int j = 0; j < 2; ++j)
#pragma unroll
            for (int r = 0; r < 4; ++r)
                sC[(wr + i * 16 + rbase + r) * 65 + (wc + j * 16 + r16)] = acc[i][j][r];
    __syncthreads();

    int row = tid >> 2, seg = tid & 3, c0 = seg * 16;
    int grow = bm + row;
    if (grow < M) {
        float v[16];
#pragma unroll
        for (int k = 0; k < 16; ++k) v[k] = sC[row * 65 + c0 + k];

        if (MODE == 1) {
            unsigned short hs[16];
#pragma unroll
            for (int k = 0; k < 16; ++k)
                hs[k] = f2bf(fmaxf(v[k] + bias[bn + c0 + k], 0.0f));
#pragma unroll
            for (int uu = 0; uu < 2; ++uu) {
                int ug = (bn + c0) / 8 + uu;
                int pu = ug ^ (grow & 7);
                *(u16x8*)(outH + (size_t)grow * 128 + pu * 8) = *(u16x8*)(hs + uu * 8);
            }
        } else {                              // MODE 2, bn < 1024
            if (bn < 512) {                   // xh -> bf16 (natural)
                unsigned short hs[16];
#pragma unroll
                for (int k = 0; k < 16; ++k) hs[k] = f2bf(v[k]);
                *(u16x8*)(outH + (size_t)grow * 512 + bn + c0)     = *(u16x8*)hs;
                *(u16x8*)(outH + (size_t)grow * 512 + bn + c0 + 8) = *(u16x8*)(hs + 8);
            } else {                          // res + (res_b+gat_b) -> bf16 (natural)
                unsigned short hs[16];
#pragma unroll
                for (int k = 0; k < 16; ++k) hs[k] = f2bf(v[k] + bias[bn - 512 + c0 + k]);
                *(u16x8*)(outL + (size_t)grow * 512 + (bn - 512) + c0)     = *(u16x8*)hs;
                *(u16x8*)(outL + (size_t)grow * 512 + (bn - 512) + c0 + 8) = *(u16x8*)(hs + 8);
            }
        }
    }
}

// ------- head-partitioned softmax+gather+residual+ELU+head-mean -> X (bf16, swizzled) ------
// h = bx & 3: workgroups round-robin across 8 XCDs (bx%8), so XCD k ALWAYS serves head
// k%4 -> each XCD's 4MB L2 permanently holds one 2.56MB head-slice of xh (R14's
// head-major order re-warmed L2 at each head transition). Wave per node; lanes =
// 4 edge-subgroups x 16 col-lanes. 32 edges per main iteration (8 gathers in flight).
__global__ __launch_bounds__(256)
void agg_k(const int* __restrict__ row_ptr, const int* __restrict__ csr,
           const float* __restrict__ a_src, const float* __restrict__ a_dst,
           const unsigned short* __restrict__ xh_b, const unsigned short* __restrict__ resb,
           unsigned short* __restrict__ Xhi)
{
    int bx = blockIdx.x;
    int h  = bx & 3;
    int ng = bx >> 2;
    int wv = threadIdx.x >> 6, lane = threadIdx.x & 63;
    int d = ng * 4 + wv;                      // 2500*4 = NN exact
    int beg = row_ptr[d], end = row_ptr[d + 1];
    int eg = lane >> 4, c16 = lane & 15;      // edge subgroup / col lane
    int cb = h * 128 + c16 * 8;               // 8 cols of head h
    float ad = a_dst[d * 4 + h];
    u16x8 rv = *(const u16x8*)(resb + (size_t)d * HF + cb);

    float acc[8];
#pragma unroll
    for (int k = 0; k < 8; ++k) acc[k] = 0.0f;
    float ssum = 0.0f;

    int e = beg;
    for (; e + 32 <= end; e += 32) {          // 8 chunks x 4 edges in flight
        int sv[8]; float w[8]; u16x8 v[8];
#pragma unroll
        for (int q = 0; q < 8; ++q) sv[q] = csr[e + q * 4 + eg];
#pragma unroll
        for (int q = 0; q < 8; ++q) v[q] = *(const u16x8*)(xh_b + (size_t)sv[q] * HF + cb);
#pragma unroll
        for (int q = 0; q < 8; ++q) {
            w[q] = __expf(leaky02(a_src[sv[q] * 4 + h] + ad));
            ssum += w[q];
        }
#pragma unroll
        for (int q = 0; q < 8; ++q)
#pragma unroll
            for (int k = 0; k < 8; ++k) acc[k] = fmaf(w[q], bf2f(v[q][k]), acc[k]);
    }
    for (; e + 16 <= end; e += 16) {          // 4 chunks x 4 edges
        int sv[4]; float w[4]; u16x8 v[4];
#pragma unroll
        for (int q = 0; q < 4; ++q) sv[q] = csr[e + q * 4 + eg];
#pragma unroll
        for (int q = 0; q < 4; ++q) v[q] = *(const u16x8*)(xh_b + (size_t)sv[q] * HF + cb);
#pragma unroll
        for (int q = 0; q < 4; ++q) {
            w[q] = __expf(leaky02(a_src[sv[q] * 4 + h] + ad));
            ssum += w[q];
        }
#pragma unroll
        for (int q = 0; q < 4; ++q)
#pragma unroll
            for (int k = 0; k < 8; ++k) acc[k] = fmaf(w[q], bf2f(v[q][k]), acc[k]);
    }
    for (; e + 4 <= end; e += 4) {
        int s = csr[e + eg];
        u16x8 v = *(const u16x8*)(xh_b + (size_t)s * HF + cb);
        float w = __expf(leaky02(a_src[s * 4 + h] + ad));
        ssum += w;
#pragma unroll
        for (int k = 0; k < 8; ++k) acc[k] = fmaf(w, bf2f(v[k]), acc[k]);
    }
    if (e + eg < end) {                       // predicated tail (<4 edges)
        int s = csr[e + eg];
        u16x8 v = *(const u16x8*)(xh_b + (size_t)s * HF + cb);
        float w = __expf(leaky02(a_src[s * 4 + h] + ad));
        ssum += w;
#pragma unroll
        for (int k = 0; k < 8; ++k) acc[k] = fmaf(w, bf2f(v[k]), acc[k]);
    }

    // combine the 4 edge-subgroups (lanes differing in bits 4..5)
#pragma unroll
    for (int off = 16; off <= 32; off <<= 1) {
        ssum += __shfl_xor(ssum, off);
#pragma unroll
        for (int k = 0; k < 8; ++k) acc[k] += __shfl_xor(acc[k], off);
    }

    float inv = 1.0f / ssum;
    float uv[8];
#pragma unroll
    for (int k = 0; k < 8; ++k) {
        float v = fmaf(acc[k], inv, bf2f(rv[k]));
        uv[k] = (v > 0.0f) ? v : expm1f(v);
    }
    float z0 = (uv[0] + uv[1] + uv[2] + uv[3]) * 0.25f;
    float z1 = (uv[4] + uv[5] + uv[6] + uv[7]) * 0.25f;
    if (eg == 0) {
        int col = h * 32 + c16 * 2;           // z-cols of head h (2 per lane, same unit)
        unsigned short h0b = f2bf(z0), h1b = f2bf(z1);
        size_t idx = (size_t)d * NHID + swz(d, col);
        *(unsigned*)(Xhi + idx) = ((unsigned)h1b << 16) | h0b;
    }
}

// ---------------- launcher ----------------
extern "C" void kernel_launch(void* const* d_in, const int* in_sizes, int n_in,
                              void* d_out, int out_size, void* d_ws, size_t ws_size,
                              hipStream_t stream)
{
    const float* x       = (const float*)d_in[0];
    const int*   ei      = (const int*)d_in[1];
    const float* enc_w   = (const float*)d_in[2];
    const float* enc_b   = (const float*)d_in[3];
    const float* res_w   = (const float*)d_in[4];
    const float* res_b   = (const float*)d_in[5];
    const float* gat_w   = (const float*)d_in[6];
    const float* att_src = (const float*)d_in[7];
    const float* att_dst = (const float*)d_in[8];
    const float* gat_b   = (const float*)d_in[9];
    const float* dec_w   = (const float*)d_in[10];
    const float* dec_b   = (const float*)d_in[11];
    float* out = (float*)d_out;

    char* p = (char*)d_ws;
    auto alloc = [&](size_t bytes) -> void* {
        void* r = (void*)p;
        p += (bytes + 255) & ~(size_t)255;
        return r;
    };
    float* a_src  = (float*)alloc(40000 * 4);
    float* a_dst  = (float*)alloc(40000 * 4);
    float* biasRG = (float*)alloc(512 * 4);
    unsigned short* xh_b = (unsigned short*)alloc(5120000 * 2);     // [N,512] bf16 (natural)
    unsigned short* resb = (unsigned short*)alloc(5120000 * 2);     // [N,512] bf16 (natural)
    unsigned short* Xhi  = (unsigned short*)alloc(1280000 * 2);     // [N,128] bf16 (swizzled)
    unsigned short* xhi  = (unsigned short*)alloc(2560000 * 2);     // x [N,256] bf16 (swizzled)
    unsigned short* ewhi = (unsigned short*)alloc(32768 * 2);       // enc_w bf16 (swizzled)
    unsigned short* fwhi = (unsigned short*)alloc(FCOLS * 128 * 2); // [1088,128] bf16 (swizzled)
    int* row_ptr = (int*)alloc(10004 * 4);
    int* csr     = (int*)alloc(170000 * 4);
    // ---- zero zone (single memset): padded dec W + cnt + cursor ----
    char* zbase = p;
    unsigned short* dwhi = (unsigned short*)alloc(8192 * 2);        // [64,128] padded (swizzled)
    int* cnt    = (int*)alloc(10000 * 4);
    int* cursor = (int*)alloc(10000 * 4);
    size_t zbytes = (size_t)(p - zbase);

    hipMemsetAsync(zbase, 0, zbytes, stream);

    // setup: conversions + attention weight rows + biasRG + edge count (one dispatch)
    fused0_k<<<TOT_B, 256, 0, stream>>>(
        x, enc_w, gat_w, res_w, dec_w, att_src, att_dst, res_b, gat_b, ei,
        xhi, ewhi, fwhi, dwhi, biasRG, cnt);

    // encoder gemm (+ merged CSR prefix scan in last y-slice)
    gemm3_k<1, 2, 1><<<dim3(157, 3), 256, 0, stream>>>(
        xhi, ewhi, enc_b, nullptr, Xhi, nullptr, nullptr, nullptr, NN,
        nullptr, cnt, row_ptr, nullptr, nullptr);

    // layer 1: fused gemm (+ merged fill_csr in last y-slice)
    gemm3_k<2, 1, 2><<<dim3(157, 18), 256, 0, stream>>>(
        Xhi, fwhi, biasRG, nullptr, xh_b, resb, a_src, a_dst, NN,
        ei, nullptr, row_ptr, cursor, csr);
    agg_k<<<10000, 256, 0, stream>>>(row_ptr, csr, a_src, a_dst, xh_b, resb, Xhi);

    // layer 2
    gemm3_k<2, 1, 0><<<dim3(157, 17), 256, 0, stream>>>(
        Xhi, fwhi, biasRG, nullptr, xh_b, resb, a_src, a_dst, NN,
        nullptr, nullptr, nullptr, nullptr, nullptr);
    agg_k<<<10000, 256, 0, stream>>>(row_ptr, csr, a_src, a_dst, xh_b, resb, Xhi);

    // decoder
    gemm3_k<0, 1, 0><<<dim3(157, 1), 256, 0, stream>>>(
        Xhi, dwhi, dec_b, out, nullptr, nullptr, nullptr, nullptr, NN,
        nullptr, nullptr, nullptr, nullptr, nullptr);
}

// Round 18
// 206.051 us; speedup vs baseline: 4.9367x; 1.1003x over previous
//
#include <hip/hip_runtime.h>
#include <math.h>

#define NN 10000
#define EE 160000
#define EP 170000          // EE + NN self loops
#define NFEAT 256
#define NHID 128
#define NH 4
#define HF 512             // NH * NHID
#define NCLASS 40
#define FCOLS 1088         // 512 xh + 512 res + 8 attn + 56 pad

typedef __attribute__((ext_vector_type(8))) short bf8;     // 8 bf16 (4 VGPR) MFMA frag
typedef __attribute__((ext_vector_type(8))) unsigned short u16x8;
typedef __attribute__((ext_vector_type(4))) float f4;

__device__ __forceinline__ float leaky02(float x) { return x >= 0.0f ? x : 0.2f * x; }

__device__ __forceinline__ unsigned short f2bf(float f) {   // RNE
    unsigned u = __builtin_bit_cast(unsigned, f);
    unsigned r = (u + 0x7FFF + ((u >> 16) & 1)) >> 16;
    return (unsigned short)r;
}
__device__ __forceinline__ float bf2f(unsigned short h) {
    return __builtin_bit_cast(float, (unsigned)h << 16);
}

// Bank-swizzled element position within a row of length K (baked into GLOBAL layout
// of MFMA operands so global->LDS staging is a LINEAR copy for global_load_lds).
__device__ __forceinline__ int swz(int row, int c) {
    return ((((c >> 3) ^ (row & 7)) << 3) | (c & 7));
}

// 16B global -> LDS direct DMA
__device__ __forceinline__ void gl_lds16(const unsigned short* g, unsigned short* l)
{
    __builtin_amdgcn_global_load_lds(
        (const __attribute__((address_space(1))) unsigned int*)g,
        (__attribute__((address_space(3))) unsigned int*)l, 16, 0, 0);
}

// ---------------- fused setup: cvt (bf16, swizzled) + attw + biasRG + edge count ----------
#define C_X   2560000
#define C_EW  (C_X + 32768)
#define C_FW  (C_EW + 131072)      // gat_w + res_w -> fw rows 0..1023
#define C_DW  (C_FW + 5120)        // dec_w [40,128]
#define CVT_B  1333                // ceil((C_DW/8)/256)
#define ATTW_B (CVT_B + 8)
#define TOT_B  (ATTW_B + 166)

__global__ __launch_bounds__(256)
void fused0_k(const float* __restrict__ x, const float* __restrict__ enc_w,
              const float* __restrict__ gat_w, const float* __restrict__ res_w,
              const float* __restrict__ dec_w,
              const float* __restrict__ att_src, const float* __restrict__ att_dst,
              const float* __restrict__ res_b, const float* __restrict__ gat_b,
              const int* __restrict__ ei,
              unsigned short* __restrict__ xhi, unsigned short* __restrict__ ewhi,
              unsigned short* __restrict__ fwhi, unsigned short* __restrict__ dwhi,
              float* __restrict__ biasRG, int* __restrict__ cnt)
{
    int bId = blockIdx.x;
    int t = threadIdx.x;
    if (bId < CVT_B) {
        int iu = bId * 256 + t;
        int i = iu * 8;
        if (i >= C_DW) return;
        const float* src = nullptr; unsigned short* ph; int j, row, c, Kd;
        if (i < C_X)       { j = i;        src = x;     ph = xhi;
                             row = j >> 8; c = j & 255; Kd = 256; }
        else if (i < C_EW) { j = i - C_X;  src = enc_w; ph = ewhi;
                             row = j >> 8; c = j & 255; Kd = 256; }
        else if (i < C_FW) { j = i - C_EW; ph = fwhi;
                             row = j >> 7; c = j & 127; Kd = 128; }
        else               { j = i - C_FW; src = dec_w; ph = dwhi;
                             row = j >> 7; c = j & 127; Kd = 128; }
        float4 v0, v1;
        if (src) { v0 = *(const float4*)(src + j); v1 = *(const float4*)(src + j + 4); }
        else {
            const float* s2 = (j < 65536) ? (gat_w + j) : (res_w + j - 65536);
            v0 = *(const float4*)s2; v1 = *(const float4*)(s2 + 4);
        }
        float vv[8] = {v0.x, v0.y, v0.z, v0.w, v1.x, v1.y, v1.z, v1.w};
        unsigned short hs[8];
#pragma unroll
        for (int k = 0; k < 8; ++k) hs[k] = f2bf(vv[k]);
        int outp = row * Kd + swz(row, c);
        *(u16x8*)(ph + outp) = *(u16x8*)hs;
    } else if (bId < ATTW_B) {
        __shared__ float sm[256];
        int b = bId - CVT_B;            // 0..7
        int is_dst = b >> 2, h = b & 3;
        const float* att = is_dst ? att_dst : att_src;
        int k = t & 127, half = t >> 7;
        float s = 0.0f;
#pragma unroll 4
        for (int c = half * 64; c < half * 64 + 64; ++c)
            s = fmaf(gat_w[(size_t)(h * 128 + c) * 128 + k], att[h * 128 + c], s);
        sm[t] = s;
        __syncthreads();
        if (t < 128) {
            float v = sm[t] + sm[t + 128];
            int R = 1024 + is_dst * 4 + h;
            fwhi[(size_t)R * 128 + swz(R, k)] = f2bf(v);
        }
        for (int i = b * 896 + t; i < (b + 1) * 896; i += 256)
            fwhi[1032 * 128 + i] = 0;
        if (b < 2) {
            int c = b * 256 + t;
            biasRG[c] = res_b[c] + gat_b[c];
        }
    } else {
        for (int e = (bId - ATTW_B) * 256 + t; e < EP; e += (TOT_B - ATTW_B) * 256) {
            int d = (e < EE) ? ei[EE + e] : (e - EE);
            atomicAdd(&cnt[d], 1);
        }
    }
}

// ---------------- bf16 MFMA GEMM (32 KB LDS) + LDS-staged epilogue ----------------
// Block 64x64, 4 waves 2x2, wave 32x32 = 2x2 MFMA tiles. acc += A*B (plain bf16).
// MODE 0: dec  -> outF[row*40+col]+bias (scalar, 40 cols)
// MODE 1: enc  -> relu(v+bias) -> bf16 (swizzled), ld=128
// MODE 2: layer-> bn<512: bf16 xh (natural, outH); 512..1023: bf16 res+biasRG (outL);
//                 1024..1031: a_src/a_dst fp32
// MERGE 1: last y-slice, x==0 runs the CSR prefix scan; MERGE 2: last y-slice fills CSR.
template<int MODE, int KTILES, int MERGE>
__global__ __launch_bounds__(256)
void gemm3_k(const unsigned short* __restrict__ A, const unsigned short* __restrict__ B,
             const float* __restrict__ bias, float* __restrict__ outF,
             unsigned short* __restrict__ outH, unsigned short* __restrict__ outL,
             float* __restrict__ a_src, float* __restrict__ a_dst, int M,
             const int* __restrict__ ei, const int* __restrict__ cnt,
             int* __restrict__ row_ptr, int* __restrict__ cursor, int* __restrict__ csr)
{
    constexpr int K = KTILES * 128;
    __shared__ __align__(16) unsigned short smem[2 * 64 * 128];   // 32 KB
    const int tid = threadIdx.x;

    if (MERGE && blockIdx.y == gridDim.y - 1) {
        if (MERGE == 1) {
            if (blockIdx.x != 0) return;
            int* smi = (int*)smem;
            int i0 = tid * 40, i1 = min(i0 + 40, NN);
            int part = 0;
            for (int i = i0; i < i1; ++i) part += cnt[i];
            smi[tid] = part;
            __syncthreads();
            for (int off = 1; off < 256; off <<= 1) {
                int v = (tid >= off) ? smi[tid - off] : 0;
                __syncthreads();
                smi[tid] += v;
                __syncthreads();
            }
            int run = smi[tid] - part;
            for (int i = i0; i < i1; ++i) { row_ptr[i] = run; run += cnt[i]; }
            if (tid == 255) row_ptr[NN] = run;
        } else {
            int stride = gridDim.x * 256;
            for (int e = blockIdx.x * 256 + tid; e < EP; e += stride) {
                int s, d;
                if (e < EE) { s = ei[e]; d = ei[EE + e]; } else { s = e - EE; d = s; }
                int pos = row_ptr[d] + atomicAdd(&cursor[d], 1);
                csr[pos] = s;
            }
        }
        return;
    }

    unsigned short* sA = smem;
    unsigned short* sB = smem + 8192;

    const int lane = tid & 63, wv = tid >> 6;
    const int wr = (wv >> 1) * 32, wc = (wv & 1) * 32;
    const int bm = blockIdx.x * 64, bn = blockIdx.y * 64;
    const int r16 = lane & 15, q4 = lane >> 4;

    f4 acc[2][2];
#pragma unroll
    for (int i = 0; i < 2; ++i)
#pragma unroll
        for (int j = 0; j < 2; ++j) acc[i][j] = (f4){0.f, 0.f, 0.f, 0.f};

    const int ra0 = wr + r16;
    const int rb0 = wc + r16;

    for (int kt = 0; kt < KTILES; ++kt) {
        if (kt) __syncthreads();
#pragma unroll
        for (int j = 0; j < 4; ++j) {
            int i = tid + j * 256;                    // unit 0..1023
            int row = i >> 4, u = i & 15;
            int arow = min(bm + row, M - 1);
            size_t ga = (size_t)arow * K + kt * 128 + u * 8;
            size_t gb = (size_t)(bn + row) * K + kt * 128 + u * 8;
            int lb = (wv * 64 + j * 256) * 8;         // wave-uniform LDS base
            gl_lds16(A + ga, sA + lb);
            gl_lds16(B + gb, sB + lb);
        }
        __syncthreads();

#pragma unroll
        for (int ks = 0; ks < 4; ++ks) {
            int u = ks * 4 + q4;
            int oa0 = ra0 * 128 + ((u ^ (ra0 & 7)) * 8);
            int ob0 = rb0 * 128 + ((u ^ (rb0 & 7)) * 8);
            int oa1 = oa0 + 16 * 128;
            int ob1 = ob0 + 16 * 128;
            bf8 A0 = *(const bf8*)(sA + oa0);
            bf8 A1 = *(const bf8*)(sA + oa1);
            bf8 B0 = *(const bf8*)(sB + ob0);
            bf8 B1 = *(const bf8*)(sB + ob1);

            acc[0][0] = __builtin_amdgcn_mfma_f32_16x16x32_bf16(A0, B0, acc[0][0], 0, 0, 0);
            acc[0][1] = __builtin_amdgcn_mfma_f32_16x16x32_bf16(A0, B1, acc[0][1], 0, 0, 0);
            acc[1][0] = __builtin_amdgcn_mfma_f32_16x16x32_bf16(A1, B0, acc[1][0], 0, 0, 0);
            acc[1][1] = __builtin_amdgcn_mfma_f32_16x16x32_bf16(A1, B1, acc[1][1], 0, 0, 0);
        }
    }

    const int rbase = q4 * 4;

    if (MODE == 0 || (MODE == 2 && bn >= 1024)) {
        // scalar epilogue: dec (40 cols) / attn columns (8 cols)
#pragma unroll
        for (int i = 0; i < 2; ++i)
#pragma unroll
            for (int j = 0; j < 2; ++j)
#pragma unroll
                for (int r = 0; r < 4; ++r) {
                    int row = bm + wr + i * 16 + rbase + r;
                    int col = bn + wc + j * 16 + r16;
                    if (row >= M) continue;
                    float v = acc[i][j][r];
                    if (MODE == 0) {
                        if (col < NCLASS)
                            outF[(size_t)row * NCLASS + col] = v + bias[col];
                    } else {
                        if (col < 1032) {
                            int h = col - 1024;
                            if (h < 4) a_src[row * 4 + h] = v;
                            else       a_dst[row * 4 + h - 4] = v;
                        }
                    }
                }
        return;
    }

    // ---- staged coalesced epilogue ----
    __syncthreads();
    float* sC = (float*)smem;                 // 64 x 65 fp32 (16.6 KB <= 32 KB)
#pragma unroll
    for (int i = 0; i < 2; ++i)
#pragma unroll
        for (int j = 0; j < 2; ++j)
#pragma unroll
            for (int r = 0; r < 4; ++r)
                sC[(wr + i * 16 + rbase + r) * 65 + (wc + j * 16 + r16)] = acc[i][j][r];
    __syncthreads();

    int row = tid >> 2, seg = tid & 3, c0 = seg * 16;
    int grow = bm + row;
    if (grow < M) {
        float v[16];
#pragma unroll
        for (int k = 0; k < 16; ++k) v[k] = sC[row * 65 + c0 + k];

        if (MODE == 1) {
            unsigned short hs[16];
#pragma unroll
            for (int k = 0; k < 16; ++k)
                hs[k] = f2bf(fmaxf(v[k] + bias[bn + c0 + k], 0.0f));
#pragma unroll
            for (int uu = 0; uu < 2; ++uu) {
                int ug = (bn + c0) / 8 + uu;
                int pu = ug ^ (grow & 7);
                *(u16x8*)(outH + (size_t)grow * 128 + pu * 8) = *(u16x8*)(hs + uu * 8);
            }
        } else {                              // MODE 2, bn < 1024
            if (bn < 512) {                   // xh -> bf16 (natural)
                unsigned short hs[16];
#pragma unroll
                for (int k = 0; k < 16; ++k) hs[k] = f2bf(v[k]);
                *(u16x8*)(outH + (size_t)grow * 512 + bn + c0)     = *(u16x8*)hs;
                *(u16x8*)(outH + (size_t)grow * 512 + bn + c0 + 8) = *(u16x8*)(hs + 8);
            } else {                          // res + (res_b+gat_b) -> bf16 (natural)
                unsigned short hs[16];
#pragma unroll
                for (int k = 0; k < 16; ++k) hs[k] = f2bf(v[k] + bias[bn - 512 + c0 + k]);
                *(u16x8*)(outL + (size_t)grow * 512 + (bn - 512) + c0)     = *(u16x8*)hs;
                *(u16x8*)(outL + (size_t)grow * 512 + (bn - 512) + c0 + 8) = *(u16x8*)(hs + 8);
            }
        }
    }
}

// ------- head-partitioned softmax+gather+residual+ELU+head-mean -> X (bf16, swizzled) ------
// Block bx: head h = bx/2500 (head-major launch order -> each quarter of the dispatch
// works a 2.56 MB xh slice that fits per-XCD L2). Wave per node; lanes = 4 edge-subgroups
// x 16 col-lanes, so ONE wave-load covers 4 edges' 256B head-rows. Cross-subgroup combine
// via shfl_xor (no LDS). [R17 lesson: h=bx&3 XCD-pinning + 32-edge unroll both regress.]
__global__ __launch_bounds__(256)
void agg_k(const int* __restrict__ row_ptr, const int* __restrict__ csr,
           const float* __restrict__ a_src, const float* __restrict__ a_dst,
           const unsigned short* __restrict__ xh_b, const unsigned short* __restrict__ resb,
           unsigned short* __restrict__ Xhi)
{
    int bx = blockIdx.x;
    int h  = bx / 2500;
    int ng = bx - h * 2500;
    int wv = threadIdx.x >> 6, lane = threadIdx.x & 63;
    int d = ng * 4 + wv;                      // 2500*4 = NN exact
    int beg = row_ptr[d], end = row_ptr[d + 1];
    int eg = lane >> 4, c16 = lane & 15;      // edge subgroup / col lane
    int cb = h * 128 + c16 * 8;               // 8 cols of head h
    float ad = a_dst[d * 4 + h];
    u16x8 rv = *(const u16x8*)(resb + (size_t)d * HF + cb);

    float acc[8];
#pragma unroll
    for (int k = 0; k < 8; ++k) acc[k] = 0.0f;
    float ssum = 0.0f;

    int e = beg;
    for (; e + 16 <= end; e += 16) {          // 4 chunks x 4 edges in flight
        int sv[4]; float w[4]; u16x8 v[4];
#pragma unroll
        for (int q = 0; q < 4; ++q) sv[q] = csr[e + q * 4 + eg];
#pragma unroll
        for (int q = 0; q < 4; ++q) v[q] = *(const u16x8*)(xh_b + (size_t)sv[q] * HF + cb);
#pragma unroll
        for (int q = 0; q < 4; ++q) {
            w[q] = __expf(leaky02(a_src[sv[q] * 4 + h] + ad));
            ssum += w[q];
        }
#pragma unroll
        for (int q = 0; q < 4; ++q)
#pragma unroll
            for (int k = 0; k < 8; ++k) acc[k] = fmaf(w[q], bf2f(v[q][k]), acc[k]);
    }
    for (; e + 4 <= end; e += 4) {
        int s = csr[e + eg];
        u16x8 v = *(const u16x8*)(xh_b + (size_t)s * HF + cb);
        float w = __expf(leaky02(a_src[s * 4 + h] + ad));
        ssum += w;
#pragma unroll
        for (int k = 0; k < 8; ++k) acc[k] = fmaf(w, bf2f(v[k]), acc[k]);
    }
    if (e + eg < end) {                       // predicated tail (<4 edges)
        int s = csr[e + eg];
        u16x8 v = *(const u16x8*)(xh_b + (size_t)s * HF + cb);
        float w = __expf(leaky02(a_src[s * 4 + h] + ad));
        ssum += w;
#pragma unroll
        for (int k = 0; k < 8; ++k) acc[k] = fmaf(w, bf2f(v[k]), acc[k]);
    }

    // combine the 4 edge-subgroups (lanes differing in bits 4..5)
#pragma unroll
    for (int off = 16; off <= 32; off <<= 1) {
        ssum += __shfl_xor(ssum, off);
#pragma unroll
        for (int k = 0; k < 8; ++k) acc[k] += __shfl_xor(acc[k], off);
    }

    float inv = 1.0f / ssum;
    float uv[8];
#pragma unroll
    for (int k = 0; k < 8; ++k) {
        float v = fmaf(acc[k], inv, bf2f(rv[k]));
        uv[k] = (v > 0.0f) ? v : expm1f(v);
    }
    float z0 = (uv[0] + uv[1] + uv[2] + uv[3]) * 0.25f;
    float z1 = (uv[4] + uv[5] + uv[6] + uv[7]) * 0.25f;
    if (eg == 0) {
        int col = h * 32 + c16 * 2;           // z-cols of head h (2 per lane, same unit)
        unsigned short h0b = f2bf(z0), h1b = f2bf(z1);
        size_t idx = (size_t)d * NHID + swz(d, col);
        *(unsigned*)(Xhi + idx) = ((unsigned)h1b << 16) | h0b;
    }
}

// ---------------- launcher ----------------
extern "C" void kernel_launch(void* const* d_in, const int* in_sizes, int n_in,
                              void* d_out, int out_size, void* d_ws, size_t ws_size,
                              hipStream_t stream)
{
    const float* x       = (const float*)d_in[0];
    const int*   ei      = (const int*)d_in[1];
    const float* enc_w   = (const float*)d_in[2];
    const float* enc_b   = (const float*)d_in[3];
    const float* res_w   = (const float*)d_in[4];
    const float* res_b   = (const float*)d_in[5];
    const float* gat_w   = (const float*)d_in[6];
    const float* att_src = (const float*)d_in[7];
    const float* att_dst = (const float*)d_in[8];
    const float* gat_b   = (const float*)d_in[9];
    const float* dec_w   = (const float*)d_in[10];
    const float* dec_b   = (const float*)d_in[11];
    float* out = (float*)d_out;

    char* p = (char*)d_ws;
    auto alloc = [&](size_t bytes) -> void* {
        void* r = (void*)p;
        p += (bytes + 255) & ~(size_t)255;
        return r;
    };
    float* a_src  = (float*)alloc(40000 * 4);
    float* a_dst  = (float*)alloc(40000 * 4);
    float* biasRG = (float*)alloc(512 * 4);
    unsigned short* xh_b = (unsigned short*)alloc(5120000 * 2);     // [N,512] bf16 (natural)
    unsigned short* resb = (unsigned short*)alloc(5120000 * 2);     // [N,512] bf16 (natural)
    unsigned short* Xhi  = (unsigned short*)alloc(1280000 * 2);     // [N,128] bf16 (swizzled)
    unsigned short* xhi  = (unsigned short*)alloc(2560000 * 2);     // x [N,256] bf16 (swizzled)
    unsigned short* ewhi = (unsigned short*)alloc(32768 * 2);       // enc_w bf16 (swizzled)
    unsigned short* fwhi = (unsigned short*)alloc(FCOLS * 128 * 2); // [1088,128] bf16 (swizzled)
    int* row_ptr = (int*)alloc(10004 * 4);
    int* csr     = (int*)alloc(170000 * 4);
    // ---- zero zone (single memset): padded dec W + cnt + cursor ----
    char* zbase = p;
    unsigned short* dwhi = (unsigned short*)alloc(8192 * 2);        // [64,128] padded (swizzled)
    int* cnt    = (int*)alloc(10000 * 4);
    int* cursor = (int*)alloc(10000 * 4);
    size_t zbytes = (size_t)(p - zbase);

    hipMemsetAsync(zbase, 0, zbytes, stream);

    // setup: conversions + attention weight rows + biasRG + edge count (one dispatch)
    fused0_k<<<TOT_B, 256, 0, stream>>>(
        x, enc_w, gat_w, res_w, dec_w, att_src, att_dst, res_b, gat_b, ei,
        xhi, ewhi, fwhi, dwhi, biasRG, cnt);

    // encoder gemm (+ merged CSR prefix scan in last y-slice)
    gemm3_k<1, 2, 1><<<dim3(157, 3), 256, 0, stream>>>(
        xhi, ewhi, enc_b, nullptr, Xhi, nullptr, nullptr, nullptr, NN,
        nullptr, cnt, row_ptr, nullptr, nullptr);

    // layer 1: fused gemm (+ merged fill_csr in last y-slice)
    gemm3_k<2, 1, 2><<<dim3(157, 18), 256, 0, stream>>>(
        Xhi, fwhi, biasRG, nullptr, xh_b, resb, a_src, a_dst, NN,
        ei, nullptr, row_ptr, cursor, csr);
    agg_k<<<10000, 256, 0, stream>>>(row_ptr, csr, a_src, a_dst, xh_b, resb, Xhi);

    // layer 2
    gemm3_k<2, 1, 0><<<dim3(157, 17), 256, 0, stream>>>(
        Xhi, fwhi, biasRG, nullptr, xh_b, resb, a_src, a_dst, NN,
        nullptr, nullptr, nullptr, nullptr, nullptr);
    agg_k<<<10000, 256, 0, stream>>>(row_ptr, csr, a_src, a_dst, xh_b, resb, Xhi);

    // decoder
    gemm3_k<0, 1, 0><<<dim3(157, 1), 256, 0, stream>>>(
        Xhi, dwhi, dec_b, out, nullptr, nullptr, nullptr, nullptr, NN,
        nullptr, nullptr, nullptr, nullptr, nullptr);
}